// Round 5
// baseline (1935.047 us; speedup 1.0000x reference)
//
#include <hip/hip_runtime.h>
#include <hip/hip_bf16.h>

namespace {

constexpr int NV = 32000;
constexpr int NE = 256;
constexpr int NH = 512;
constexpr int NB = 32;
constexpr int NT = 64;
constexpr int NG = 3 * NH;    // 1536
constexpr int NM = NB * NT;   // 2048
constexpr int SOS = 1;

typedef _Float16 f16_t;
typedef _Float16 f16x8 __attribute__((ext_vector_type(8)));
typedef _Float16 f16x2 __attribute__((ext_vector_type(2)));
typedef float f32x4 __attribute__((ext_vector_type(4)));

typedef __attribute__((address_space(1))) void gvoid_t;
typedef __attribute__((address_space(3))) void lvoid_t;

union P8 { f16_t h[4]; unsigned long long u; };

// fragment-order offset of h[u][b] inside a 512x32 f16 step buffer.
// B-frag of mfma_f32_16x16x32_f16: lane l holds col n=l&15, k=(l>>4)*8+j.
__device__ __forceinline__ int fragoff(int u, int b) {
  return ((b >> 4) * 16 + (u >> 5)) * 512 +
         ((((u >> 3) & 3) * 16) + (b & 15)) * 8 + (u & 7);
}

__device__ __forceinline__ void load_wf(const float* wrow, f16x8* wf) {
  #pragma unroll
  for (int kc = 0; kc < 16; ++kc) {
    f32x4 a = *(const f32x4*)(wrow + kc * 32);
    f32x4 c = *(const f32x4*)(wrow + kc * 32 + 4);
    f16x8 w;
    w[0] = (f16_t)a[0]; w[1] = (f16_t)a[1]; w[2] = (f16_t)a[2]; w[3] = (f16_t)a[3];
    w[4] = (f16_t)c[0]; w[5] = (f16_t)c[1]; w[6] = (f16_t)c[2]; w[7] = (f16_t)c[3];
    wf[kc] = w;
  }
}

__device__ __forceinline__ float sigm(float x) { return 1.f / (1.f + __expf(-x)); }

__device__ __forceinline__ void wait_ge(int* p, int target) {
  while (__hip_atomic_load(p, __ATOMIC_RELAXED, __HIP_MEMORY_SCOPE_AGENT) < target)
    __builtin_amdgcn_s_sleep(1);
}

__device__ __forceinline__ void store8(f16_t* dst, unsigned long long v) {
  __hip_atomic_store((unsigned long long*)dst, v, __ATOMIC_RELAXED,
                     __HIP_MEMORY_SCOPE_AGENT);   // sc1 write-through: L2 stays clean
}

// ---------------- prologue kernels ----------------

__global__ __launch_bounds__(256) void k_hinit(const float* __restrict__ eh,
                                               f16_t* __restrict__ hb0,
                                               f16_t* __restrict__ hb1) {
  int idx = blockIdx.x * 256 + threadIdx.x;   // l*16384 + b*512 + u
  int u = idx & 511;
  int b = (idx >> 9) & 31;
  int l = idx >> 14;
  f16_t v = (f16_t)eh[idx];
  (l ? hb1 : hb0)[fragoff(u, b)] = v;
}

__global__ __launch_bounds__(256) void k_wcvt(const float* __restrict__ w,
                                              f16_t* __restrict__ wb) {
  int idx = blockIdx.x * 256 + threadIdx.x;   // < NV*NH/4
  f32x4 v = ((const f32x4*)w)[idx];
  f16x2 o0, o1;
  o0[0] = (f16_t)v[0]; o0[1] = (f16_t)v[1];
  o1[0] = (f16_t)v[2]; o1[1] = (f16_t)v[3];
  ((f16x2*)wb)[2 * idx] = o0;
  ((f16x2*)wb)[2 * idx + 1] = o1;
}

__global__ __launch_bounds__(256) void k_gi0(const int* __restrict__ tgt,
                                             const float* __restrict__ emb,
                                             const float* __restrict__ Wih0,
                                             const float* __restrict__ bih0,
                                             f16_t* __restrict__ Gi0) {
  __shared__ float xs[NE * NB];   // [e][b]
  __shared__ int toks[NB];
  const int t = blockIdx.y;
  const int tid = threadIdx.x;
  if (tid < NB) toks[tid] = (t == 0) ? SOS : tgt[tid * NT + (t - 1)];
  __syncthreads();
  {
    const int b = tid >> 3, e0 = (tid & 7) * 32;
    const float* er = emb + (size_t)toks[b] * NE + e0;
    #pragma unroll 8
    for (int i = 0; i < 32; ++i) {
      float v = er[i];
      xs[(e0 + i) * NB + b] = v > 0.f ? v : 0.f;
    }
  }
  __syncthreads();
  const int b = tid & 31;
  #pragma unroll
  for (int jj = 0; jj < 8; ++jj) {
    const int j = blockIdx.x * 64 + jj * 8 + (tid >> 5);
    float acc = bih0[j];
    const f32x4* wr = (const f32x4*)(Wih0 + (size_t)j * NE);
    #pragma unroll 4
    for (int e4 = 0; e4 < NE / 4; ++e4) {
      f32x4 w = wr[e4];
      acc += w[0] * xs[(4 * e4 + 0) * NB + b] + w[1] * xs[(4 * e4 + 1) * NB + b]
           + w[2] * xs[(4 * e4 + 2) * NB + b] + w[3] * xs[(4 * e4 + 3) * NB + b];
    }
    Gi0[((size_t)t * NG + j) * NB + b] = (f16_t)acc;
  }
}

// ---------------- persistent MFMA recurrence (round 5) ----------------
// blocks 0..3: layer 0, 128 units each, 16 waves = (utile 0..7) x (bhalf 0..1).
// blocks 4..11: layer 1, 64 units each, 16 waves = (utile 0..3)x(bhalf)x(mat).
// Each wave computes ALL 3 gates of its (u-tile, b-half) -> gate math stays
// in-register (L0 has zero LDS traffic). All inter-block data written via
// relaxed agent atomic 8B stores (write-through, L2 clean -> cheap release).

__global__ __launch_bounds__(1024) void k_rnn2(
    const f16_t* __restrict__ Gi0,
    const float* __restrict__ Whh0, const float* __restrict__ bhh0,
    const float* __restrict__ Wih1, const float* __restrict__ bih1,
    const float* __restrict__ Whh1, const float* __restrict__ bhh1,
    const float* __restrict__ eh,
    f16_t* __restrict__ hb0, f16_t* __restrict__ hb1,
    f16_t* __restrict__ Abf, float* __restrict__ hfin,
    int* c0, int* c1) {
  const int tid = threadIdx.x;
  const int w = tid >> 6, lane = tid & 63;
  const int bid = blockIdx.x;

  if (bid < 4) {
    // ---------------- layer 0 ----------------
    const int ug = bid * 128;
    const int utile = w >> 1, bhalf = w & 1;
    const int u0 = ug + utile * 16 + (lane >> 4) * 4;
    const int b  = bhalf * 16 + (lane & 15);

    f16x8 wf[3][16];
    #pragma unroll
    for (int gg = 0; gg < 3; ++gg)
      load_wf(Whh0 + (size_t)(gg * 512 + ug + utile * 16 + (lane & 15)) * NH +
              (lane >> 4) * 8, wf[gg]);

    float hprev[4], br[4], bz[4], bn[4];
    #pragma unroll
    for (int r = 0; r < 4; ++r) {
      hprev[r] = eh[b * NH + u0 + r];
      br[r] = bhh0[u0 + r]; bz[r] = bhh0[512 + u0 + r]; bn[r] = bhh0[1024 + u0 + r];
    }

    for (int t = 0; t < NT; ++t) {
      float gr[4], gz[4], gn[4];
      {
        const f16_t* gi = Gi0 + (size_t)t * NG * NB;   // prefetch overlaps the wait
        #pragma unroll
        for (int r = 0; r < 4; ++r) {
          gr[r] = (float)gi[(u0 + r) * NB + b];
          gz[r] = (float)gi[(512 + u0 + r) * NB + b];
          gn[r] = (float)gi[(1024 + u0 + r) * NB + b];
        }
      }
      if (t > 0 && tid == 0) {
        wait_ge(c0 + t - 1, 4);
        __builtin_amdgcn_fence(__ATOMIC_ACQUIRE, "agent");
      }
      __syncthreads();
      const f16_t* hbp = hb0 + (size_t)t * 16384 + bhalf * 8192;
      f32x4 a0 = {0.f,0.f,0.f,0.f}, a1 = {0.f,0.f,0.f,0.f}, a2 = {0.f,0.f,0.f,0.f};
      #pragma unroll
      for (int kc = 0; kc < 16; ++kc) {
        f16x8 bf = *(const f16x8*)(hbp + kc * 512 + lane * 8);
        a0 = __builtin_amdgcn_mfma_f32_16x16x32_f16(wf[0][kc], bf, a0, 0, 0, 0);
        a1 = __builtin_amdgcn_mfma_f32_16x16x32_f16(wf[1][kc], bf, a1, 0, 0, 0);
        a2 = __builtin_amdgcn_mfma_f32_16x16x32_f16(wf[2][kc], bf, a2, 0, 0, 0);
      }
      P8 p;
      #pragma unroll
      for (int r = 0; r < 4; ++r) {
        float rr = sigm(gr[r] + a0[r] + br[r]);
        float zz = sigm(gz[r] + a1[r] + bz[r]);
        float nn = tanhf(gn[r] + rr * (a2[r] + bn[r]));
        float h = (1.f - zz) * nn + zz * hprev[r];
        hprev[r] = h;
        p.h[r] = (f16_t)h;
      }
      store8(hb0 + (size_t)(t + 1) * 16384 + fragoff(u0, b), p.u);
      if (t == NT - 1)
        *(f32x4*)(hfin + b * NH + u0) = (f32x4){hprev[0], hprev[1], hprev[2], hprev[3]};
      __syncthreads();
      if (tid == 0)
        __hip_atomic_fetch_add(c0 + t, 1, __ATOMIC_RELEASE, __HIP_MEMORY_SCOPE_AGENT);
    }
  } else {
    // ---------------- layer 1 ----------------
    __shared__ float part[8][12][64];   // mat=1 -> mat=0 mailbox, conflict-free
    const int ug = (bid - 4) * 64;
    const int utile = w >> 2, bhalf = (w >> 1) & 1, mat = w & 1;
    const int pp = w >> 1;
    const int u0 = ug + utile * 16 + (lane >> 4) * 4;
    const int b  = bhalf * 16 + (lane & 15);

    const float* W = mat ? Whh1 : Wih1;
    f16x8 wf[3][16];
    #pragma unroll
    for (int gg = 0; gg < 3; ++gg)
      load_wf(W + (size_t)(gg * 512 + ug + utile * 16 + (lane & 15)) * NH +
              (lane >> 4) * 8, wf[gg]);

    float hprev[4], bi[3][4], bh[3][4];
    if (mat == 0) {
      #pragma unroll
      for (int r = 0; r < 4; ++r) {
        hprev[r] = eh[16384 + b * NH + u0 + r];
        #pragma unroll
        for (int gg = 0; gg < 3; ++gg) {
          bi[gg][r] = bih1[gg * 512 + u0 + r];
          bh[gg][r] = bhh1[gg * 512 + u0 + r];
        }
      }
    }

    for (int t = 0; t < NT; ++t) {
      if (tid == 0) {
        wait_ge(c0 + t, 4);
        if (t > 0) wait_ge(c1 + t - 1, 8);
        __builtin_amdgcn_fence(__ATOMIC_ACQUIRE, "agent");
      }
      __syncthreads();
      const f16_t* src = (mat ? hb1 + (size_t)t * 16384
                              : hb0 + (size_t)(t + 1) * 16384) + bhalf * 8192;
      f32x4 a0 = {0.f,0.f,0.f,0.f}, a1 = {0.f,0.f,0.f,0.f}, a2 = {0.f,0.f,0.f,0.f};
      #pragma unroll
      for (int kc = 0; kc < 16; ++kc) {
        f16x8 bf = *(const f16x8*)(src + kc * 512 + lane * 8);
        a0 = __builtin_amdgcn_mfma_f32_16x16x32_f16(wf[0][kc], bf, a0, 0, 0, 0);
        a1 = __builtin_amdgcn_mfma_f32_16x16x32_f16(wf[1][kc], bf, a1, 0, 0, 0);
        a2 = __builtin_amdgcn_mfma_f32_16x16x32_f16(wf[2][kc], bf, a2, 0, 0, 0);
      }
      if (mat) {
        #pragma unroll
        for (int r = 0; r < 4; ++r) {
          part[pp][r][lane]     = a0[r];
          part[pp][4 + r][lane] = a1[r];
          part[pp][8 + r][lane] = a2[r];
        }
      }
      __syncthreads();
      if (mat == 0) {
        P8 p;
        #pragma unroll
        for (int r = 0; r < 4; ++r) {
          float hr = part[pp][r][lane]     + bh[0][r];
          float hz = part[pp][4 + r][lane] + bh[1][r];
          float hn = part[pp][8 + r][lane] + bh[2][r];
          float rr = sigm(a0[r] + bi[0][r] + hr);
          float zz = sigm(a1[r] + bi[1][r] + hz);
          float nn = tanhf(a2[r] + bi[2][r] + rr * hn);
          float h = (1.f - zz) * nn + zz * hprev[r];
          hprev[r] = h;
          p.h[r] = (f16_t)h;
        }
        store8(hb1 + (size_t)(t + 1) * 16384 + fragoff(u0, b), p.u);
        store8(Abf + ((size_t)(b * NT + t)) * 512 + u0, p.u);
        if (t == NT - 1)
          *(f32x4*)(hfin + 16384 + b * NH + u0) =
              (f32x4){hprev[0], hprev[1], hprev[2], hprev[3]};
      }
      __syncthreads();
      if (tid == 0)
        __hip_atomic_fetch_add(c1 + t, 1, __ATOMIC_RELEASE, __HIP_MEMORY_SCOPE_AGENT);
    }
  }
}

// ---------------- output projection (f16 MFMA, m97-style) ----------------

__global__ __launch_bounds__(256) void k_gemm(const f16_t* __restrict__ A,
                                              const f16_t* __restrict__ Bw,
                                              const float* __restrict__ bout,
                                              float* __restrict__ C) {
  __shared__ __align__(16) f16_t As[2][128 * 32];
  __shared__ __align__(16) f16_t Bs[2][128 * 32];
  const int n0 = blockIdx.x * 128;
  const int m0 = blockIdx.y * 128;
  const int tid = threadIdx.x;
  const int wave = tid >> 6;
  const int lane = tid & 63;
  const int r_in = lane >> 2;
  const int c8 = (lane & 3) * 8;

  const f16_t* Ag = A  + (size_t)(m0 + wave * 32 + r_in) * NH + c8;
  const f16_t* Bg = Bw + (size_t)(n0 + wave * 32 + r_in) * NH + c8;

  auto stage = [&](int buf, int kk) {
    f16_t* la = &As[buf][(wave * 32) * 32];
    f16_t* lb = &Bs[buf][(wave * 32) * 32];
    __builtin_amdgcn_global_load_lds((gvoid_t*)(Ag + kk),            (lvoid_t*)la,             16, 0, 0);
    __builtin_amdgcn_global_load_lds((gvoid_t*)(Ag + kk + 16 * NH),  (lvoid_t*)(la + 16 * 32), 16, 0, 0);
    __builtin_amdgcn_global_load_lds((gvoid_t*)(Bg + kk),            (lvoid_t*)lb,             16, 0, 0);
    __builtin_amdgcn_global_load_lds((gvoid_t*)(Bg + kk + 16 * NH),  (lvoid_t*)(lb + 16 * 32), 16, 0, 0);
  };

  f32x4 acc[4][4];
  #pragma unroll
  for (int i = 0; i < 4; ++i)
    #pragma unroll
    for (int j = 0; j < 4; ++j)
      acc[i][j] = (f32x4){0.f, 0.f, 0.f, 0.f};

  const int wm = (wave >> 1) * 64;
  const int wn = (wave & 1) * 64;
  const int arow = lane & 15;
  const int kg = (lane >> 4) * 8;

  stage(0, 0);
  __syncthreads();
  for (int kt = 0; kt < NH / 32; ++kt) {
    const int buf = kt & 1;
    if (kt + 1 < NH / 32) stage(buf ^ 1, (kt + 1) * 32);
    f16x8 af[4], bfr[4];
    #pragma unroll
    for (int i = 0; i < 4; ++i) {
      af[i]  = *(const f16x8*)&As[buf][(wm + i * 16 + arow) * 32 + kg];
      bfr[i] = *(const f16x8*)&Bs[buf][(wn + i * 16 + arow) * 32 + kg];
    }
    #pragma unroll
    for (int i = 0; i < 4; ++i)
      #pragma unroll
      for (int j = 0; j < 4; ++j)
        acc[i][j] = __builtin_amdgcn_mfma_f32_16x16x32_f16(af[i], bfr[j], acc[i][j], 0, 0, 0);
    __syncthreads();
  }

  const int crow = (lane >> 4) * 4;
  const int ccol = lane & 15;
  #pragma unroll
  for (int j = 0; j < 4; ++j) {
    const int gcol = n0 + wn + j * 16 + ccol;
    const float bb = bout[gcol];
    #pragma unroll
    for (int i = 0; i < 4; ++i) {
      const int grow = m0 + wm + i * 16 + crow;
      #pragma unroll
      for (int r = 0; r < 4; ++r)
        C[(size_t)(grow + r) * NV + gcol] = acc[i][j][r] + bb;
    }
  }
}

// ---------------- in-place row log_softmax ----------------

__global__ __launch_bounds__(256) void k_lsm(float* __restrict__ out) {
  __shared__ f16_t row[NV];
  __shared__ float redm[4], reds[4];
  const int m = blockIdx.x;
  float* p = out + (size_t)m * NV;
  const int tid = threadIdx.x;
  float mx = -3.0e38f;
  for (int i = tid; i < NV; i += 256) {
    float x = p[i];
    row[i] = (f16_t)x;
    mx = fmaxf(mx, x);
  }
  #pragma unroll
  for (int o = 1; o < 64; o <<= 1) mx = fmaxf(mx, __shfl_xor(mx, o, 64));
  if ((tid & 63) == 0) redm[tid >> 6] = mx;
  __syncthreads();
  mx = fmaxf(fmaxf(redm[0], redm[1]), fmaxf(redm[2], redm[3]));
  float s = 0.f;
  for (int i = tid; i < NV; i += 256) s += __expf((float)row[i] - mx);
  #pragma unroll
  for (int o = 1; o < 64; o <<= 1) s += __shfl_xor(s, o, 64);
  if ((tid & 63) == 0) reds[tid >> 6] = s;
  __syncthreads();
  const float lse = mx + __logf(reds[0] + reds[1] + reds[2] + reds[3]);
  for (int i = tid; i < NV; i += 256) p[i] = (float)row[i] - lse;
}

// ws layout (bytes)
constexpr size_t WS_C0  = 0;
constexpr size_t WS_C1  = 256;
constexpr size_t WS_GI0 = 1024;
constexpr size_t WS_HB0 = WS_GI0 + sizeof(f16_t) * (size_t)NT * NG * NB;       // 6.29 MB
constexpr size_t WS_HB1 = WS_HB0 + sizeof(f16_t) * (size_t)(NT + 1) * NH * NB; // +2.13 MB
constexpr size_t WS_ABF = WS_HB1 + sizeof(f16_t) * (size_t)(NT + 1) * NH * NB;
constexpr size_t WS_WF  = WS_ABF + sizeof(f16_t) * (size_t)NM * NH;

}  // namespace

extern "C" void kernel_launch(void* const* d_in, const int* in_sizes, int n_in,
                              void* d_out, int out_size, void* d_ws, size_t ws_size,
                              hipStream_t stream) {
  const float* enc_h = (const float*)d_in[1];
  const int*   tgt   = (const int*)d_in[2];
  const float* emb   = (const float*)d_in[3];
  const float* Wih0  = (const float*)d_in[4];
  const float* Whh0  = (const float*)d_in[5];
  const float* bih0  = (const float*)d_in[6];
  const float* bhh0  = (const float*)d_in[7];
  const float* Wih1  = (const float*)d_in[8];
  const float* Whh1  = (const float*)d_in[9];
  const float* bih1  = (const float*)d_in[10];
  const float* bhh1  = (const float*)d_in[11];
  const float* Wout  = (const float*)d_in[12];
  const float* bout  = (const float*)d_in[13];

  char* ws = (char*)d_ws;
  int*    c0   = (int*)(ws + WS_C0);
  int*    c1   = (int*)(ws + WS_C1);
  f16_t*  Gi0  = (f16_t*)(ws + WS_GI0);
  f16_t*  hb0  = (f16_t*)(ws + WS_HB0);
  f16_t*  hb1  = (f16_t*)(ws + WS_HB1);
  f16_t*  Abf  = (f16_t*)(ws + WS_ABF);
  f16_t*  Wf   = (f16_t*)(ws + WS_WF);

  float* out  = (float*)d_out;
  float* hfin = out + (size_t)NM * NV;

  hipMemsetAsync(ws, 0, 1024, stream);
  k_hinit<<<(2 * NB * NH) / 256, 256, 0, stream>>>(enc_h, hb0, hb1);
  k_gi0<<<dim3(NG / 64, NT), 256, 0, stream>>>(tgt, emb, Wih0, bih0, Gi0);
  k_rnn2<<<12, 1024, 0, stream>>>(Gi0, Whh0, bhh0, Wih1, bih1, Whh1, bhh1,
                                  enc_h, hb0, hb1, Abf, hfin, c0, c1);
  k_wcvt<<<(NV * NH / 4) / 256, 256, 0, stream>>>(Wout, Wf);
  k_gemm<<<dim3(NV / 128, NM / 128), 256, 0, stream>>>(Abf, Wf, bout, out);
  k_lsm<<<NM, 256, 0, stream>>>(out);
}

// Round 6
// 971.081 us; speedup vs baseline: 1.9927x; 1.9927x over previous
//
#include <hip/hip_runtime.h>
#include <hip/hip_bf16.h>

namespace {

constexpr int NV = 32000;
constexpr int NE = 256;
constexpr int NH = 512;
constexpr int NB = 32;
constexpr int NT = 64;
constexpr int NG = 3 * NH;    // 1536
constexpr int NM = NB * NT;   // 2048
constexpr int SOS = 1;

typedef _Float16 f16_t;
typedef _Float16 f16x8 __attribute__((ext_vector_type(8)));
typedef _Float16 f16x2 __attribute__((ext_vector_type(2)));
typedef float f32x4 __attribute__((ext_vector_type(4)));

typedef __attribute__((address_space(1))) void gvoid_t;
typedef __attribute__((address_space(3))) void lvoid_t;

// fragment-order offset of h[u][b] inside a 512x32 f16 step buffer.
// B-frag of mfma_f32_16x16x32_f16: lane l holds col n=l&15, k=(l>>4)*8+j.
__device__ __forceinline__ int fragoff(int u, int b) {
  return ((b >> 4) * 16 + (u >> 5)) * 512 +
         ((((u >> 3) & 3) * 16) + (b & 15)) * 8 + (u & 7);
}

__device__ __forceinline__ void load_wf(const float* wrow, f16x8* wf) {
  #pragma unroll
  for (int kc = 0; kc < 16; ++kc) {
    f32x4 a = *(const f32x4*)(wrow + kc * 32);
    f32x4 c = *(const f32x4*)(wrow + kc * 32 + 4);
    f16x8 w;
    w[0] = (f16_t)a[0]; w[1] = (f16_t)a[1]; w[2] = (f16_t)a[2]; w[3] = (f16_t)a[3];
    w[4] = (f16_t)c[0]; w[5] = (f16_t)c[1]; w[6] = (f16_t)c[2]; w[7] = (f16_t)c[3];
    wf[kc] = w;
  }
}

__device__ __forceinline__ float sigm(float x) { return 1.f / (1.f + __expf(-x)); }

// Per-block flag words, each on its own 64B line (int stride 16).
// Poll with RELAXED agent loads (no per-iteration invalidate); publish with a
// RELEASE STORE (no RMW -> no cross-XCD cacheline serialization, the R4 killer).
__device__ __forceinline__ void wait_flag(int* p, int target) {
  while (__hip_atomic_load(p, __ATOMIC_RELAXED, __HIP_MEMORY_SCOPE_AGENT) < target)
    __builtin_amdgcn_s_sleep(1);
}

// ---------------- prologue kernels ----------------

__global__ __launch_bounds__(256) void k_hinit(const float* __restrict__ eh,
                                               f16_t* __restrict__ hb0,
                                               f16_t* __restrict__ hb1) {
  int idx = blockIdx.x * 256 + threadIdx.x;   // l*16384 + b*512 + u
  int u = idx & 511;
  int b = (idx >> 9) & 31;
  int l = idx >> 14;
  f16_t v = (f16_t)eh[idx];
  (l ? hb1 : hb0)[fragoff(u, b)] = v;
}

__global__ __launch_bounds__(256) void k_wcvt(const float* __restrict__ w,
                                              f16_t* __restrict__ wb) {
  int idx = blockIdx.x * 256 + threadIdx.x;   // < NV*NH/4
  f32x4 v = ((const f32x4*)w)[idx];
  f16x2 o0, o1;
  o0[0] = (f16_t)v[0]; o0[1] = (f16_t)v[1];
  o1[0] = (f16_t)v[2]; o1[1] = (f16_t)v[3];
  ((f16x2*)wb)[2 * idx] = o0;
  ((f16x2*)wb)[2 * idx + 1] = o1;
}

__global__ __launch_bounds__(256) void k_gi0(const int* __restrict__ tgt,
                                             const float* __restrict__ emb,
                                             const float* __restrict__ Wih0,
                                             const float* __restrict__ bih0,
                                             f16_t* __restrict__ Gi0) {
  __shared__ float xs[NE * NB];   // [e][b]
  __shared__ int toks[NB];
  const int t = blockIdx.y;
  const int tid = threadIdx.x;
  if (tid < NB) toks[tid] = (t == 0) ? SOS : tgt[tid * NT + (t - 1)];
  __syncthreads();
  {
    const int b = tid >> 3, e0 = (tid & 7) * 32;
    const float* er = emb + (size_t)toks[b] * NE + e0;
    #pragma unroll 8
    for (int i = 0; i < 32; ++i) {
      float v = er[i];
      xs[(e0 + i) * NB + b] = v > 0.f ? v : 0.f;
    }
  }
  __syncthreads();
  const int b = tid & 31;
  #pragma unroll
  for (int jj = 0; jj < 8; ++jj) {
    const int j = blockIdx.x * 64 + jj * 8 + (tid >> 5);
    float acc = bih0[j];
    const f32x4* wr = (const f32x4*)(Wih0 + (size_t)j * NE);
    #pragma unroll 4
    for (int e4 = 0; e4 < NE / 4; ++e4) {
      f32x4 w = wr[e4];
      acc += w[0] * xs[(4 * e4 + 0) * NB + b] + w[1] * xs[(4 * e4 + 1) * NB + b]
           + w[2] * xs[(4 * e4 + 2) * NB + b] + w[3] * xs[(4 * e4 + 3) * NB + b];
    }
    Gi0[((size_t)t * NG + j) * NB + b] = (f16_t)acc;
  }
}

// ---------------- persistent MFMA recurrence (round-4 structure) ----------------
// blocks 0..7: layer 0 (64 units each).  blocks 8..23: layer 1 (32 units each).
// h passed via per-step frag-order f16 buffers hb0[t], hb1[t] (t=0 is initial).
// Sync (round 6): per-block flag lines + parallel polls + release-store publish.

__global__ __launch_bounds__(768) void k_rnn2(
    const f16_t* __restrict__ Gi0,
    const float* __restrict__ Whh0, const float* __restrict__ bhh0,
    const float* __restrict__ Wih1, const float* __restrict__ bih1,
    const float* __restrict__ Whh1, const float* __restrict__ bhh1,
    const float* __restrict__ eh,
    f16_t* __restrict__ hb0, f16_t* __restrict__ hb1,
    f16_t* __restrict__ Abf, float* __restrict__ hfin,
    int* f0, int* f1) {
  __shared__ __align__(16) float gLDS[6144];      // 24 KB
  __shared__ __align__(16) f16_t hstage[2048];    // 4 KB
  __shared__ __align__(16) f16_t astage[1024];    // 2 KB
  const int tid = threadIdx.x;
  const int wave = tid >> 6, lane = tid & 63;
  const int bid = blockIdx.x;
  const int eb = tid & 31, eu0 = (tid >> 5) & 15;

  if (bid < 8) {
    // ---------------- layer 0 ----------------
    const int ug = bid * 64;
    const int gate = wave >> 2, tile = wave & 3;
    const int row = gate * 512 + ug + tile * 16 + (lane & 15);
    f16x8 wf[16];
    load_wf(Whh0 + (size_t)row * NH + (lane >> 4) * 8, wf);

    float hprev[4], br[4], bz[4], bn[4];
    if (tid < 512) {
      #pragma unroll
      for (int i = 0; i < 4; ++i) {
        int u = ug + eu0 + i * 16;
        hprev[i] = eh[eb * NH + u];
        br[i] = bhh0[u]; bz[i] = bhh0[512 + u]; bn[i] = bhh0[1024 + u];
      }
    }

    for (int t = 0; t < NT; ++t) {
      float gr[4], gz[4], gn[4];
      if (tid < 512) {                       // prefetch gi (overlaps the wait)
        const f16_t* g = Gi0 + (size_t)t * NG * NB;
        #pragma unroll
        for (int i = 0; i < 4; ++i) {
          int u = ug + eu0 + i * 16;
          gr[i] = (float)g[u * NB + eb];
          gz[i] = (float)g[(512 + u) * NB + eb];
          gn[i] = (float)g[(1024 + u) * NB + eb];
        }
      }
      if (t > 0) {
        if (tid < 8) wait_flag(f0 + tid * 16, t);   // all 8 flags polled in parallel
        if (tid == 0) __builtin_amdgcn_fence(__ATOMIC_ACQUIRE, "agent");
      }
      __syncthreads();
      const f16_t* hb = hb0 + (size_t)t * 16384;
      f32x4 acc0 = {0.f, 0.f, 0.f, 0.f}, acc1 = {0.f, 0.f, 0.f, 0.f};
      #pragma unroll
      for (int kc = 0; kc < 16; ++kc) {
        f16x8 b0 = *(const f16x8*)(hb + kc * 512 + lane * 8);
        f16x8 b1 = *(const f16x8*)(hb + (16 + kc) * 512 + lane * 8);
        acc0 = __builtin_amdgcn_mfma_f32_16x16x32_f16(wf[kc], b0, acc0, 0, 0, 0);
        acc1 = __builtin_amdgcn_mfma_f32_16x16x32_f16(wf[kc], b1, acc1, 0, 0, 0);
      }
      {
        const int m0 = (lane >> 4) * 4, col = lane & 15;
        #pragma unroll
        for (int r = 0; r < 4; ++r) {
          int ul = tile * 16 + m0 + r;
          gLDS[(gate * 64 + ul) * 32 + col] = acc0[r];
          gLDS[(gate * 64 + ul) * 32 + 16 + col] = acc1[r];
        }
      }
      __syncthreads();
      if (tid < 512) {
        #pragma unroll
        for (int i = 0; i < 4; ++i) {
          int ul = eu0 + i * 16;
          float rt = gLDS[(0 * 64 + ul) * 32 + eb];
          float zt = gLDS[(1 * 64 + ul) * 32 + eb];
          float nt_ = gLDS[(2 * 64 + ul) * 32 + eb];
          float r = sigm(gr[i] + rt + br[i]);
          float z = sigm(gz[i] + zt + bz[i]);
          float n = tanhf(gn[i] + r * (nt_ + bn[i]));
          float hnew = (1.f - z) * n + z * hprev[i];
          hprev[i] = hnew;
          hstage[((eb >> 4) * 2 + (ul >> 5)) * 512 +
                 ((((ul >> 3) & 3) * 16) + (eb & 15)) * 8 + (ul & 7)] = (f16_t)hnew;
          if (t == NT - 1) hfin[eb * NH + ug + ul] = hnew;
        }
      }
      __syncthreads();
      if (tid < 512) {
        const int chunk = tid >> 7, w = tid & 127;
        const uint2 v = *(const uint2*)(hstage + chunk * 512 + w * 4);
        *(uint2*)(hb0 + (size_t)(t + 1) * 16384 +
                  ((chunk >> 1) * 16 + (ug >> 5) + (chunk & 1)) * 512 + w * 4) = v;
      }
      __syncthreads();
      if (tid == 0)
        __hip_atomic_store(f0 + bid * 16, t + 1, __ATOMIC_RELEASE,
                           __HIP_MEMORY_SCOPE_AGENT);
    }
  } else {
    // ---------------- layer 1 ----------------
    const int g = bid - 8, ug = g * 32;
    const int mm = wave >= 6;                 // 0: Wih1 (x=h0), 1: Whh1 (h1)
    const int w6 = mm ? wave - 6 : wave;
    const int gate = w6 >> 1, tile = w6 & 1;
    const int row = gate * 512 + ug + tile * 16 + (lane & 15);
    const float* W = mm ? Whh1 : Wih1;
    f16x8 wf[16];
    load_wf(W + (size_t)row * NH + (lane >> 4) * 8, wf);

    float hprev[2], bir[2], biz[2], bin_[2], bhr[2], bhz[2], bhn[2];
    if (tid < 512) {
      #pragma unroll
      for (int i = 0; i < 2; ++i) {
        int u = ug + eu0 + i * 16;
        hprev[i] = eh[16384 + eb * NH + u];
        bir[i] = bih1[u]; biz[i] = bih1[512 + u]; bin_[i] = bih1[1024 + u];
        bhr[i] = bhh1[u]; bhz[i] = bhh1[512 + u]; bhn[i] = bhh1[1024 + u];
      }
    }

    for (int t = 0; t < NT; ++t) {
      if (tid < 24) {                        // parallel poll: 8x f0, 16x f1
        int* p   = (tid < 8) ? (f0 + tid * 16) : (f1 + (tid - 8) * 16);
        int tgt  = (tid < 8) ? (t + 1) : t;
        wait_flag(p, tgt);
      }
      if (tid == 0) __builtin_amdgcn_fence(__ATOMIC_ACQUIRE, "agent");
      __syncthreads();
      const f16_t* hb = mm ? (hb1 + (size_t)t * 16384)
                           : (hb0 + (size_t)(t + 1) * 16384);
      f32x4 acc0 = {0.f, 0.f, 0.f, 0.f}, acc1 = {0.f, 0.f, 0.f, 0.f};
      #pragma unroll
      for (int kc = 0; kc < 16; ++kc) {
        f16x8 b0 = *(const f16x8*)(hb + kc * 512 + lane * 8);
        f16x8 b1 = *(const f16x8*)(hb + (16 + kc) * 512 + lane * 8);
        acc0 = __builtin_amdgcn_mfma_f32_16x16x32_f16(wf[kc], b0, acc0, 0, 0, 0);
        acc1 = __builtin_amdgcn_mfma_f32_16x16x32_f16(wf[kc], b1, acc1, 0, 0, 0);
      }
      {
        const int m0 = (lane >> 4) * 4, col = lane & 15;
        #pragma unroll
        for (int r = 0; r < 4; ++r) {
          int ul = tile * 16 + m0 + r;
          gLDS[((mm * 3 + gate) * 32 + ul) * 32 + col] = acc0[r];
          gLDS[((mm * 3 + gate) * 32 + ul) * 32 + 16 + col] = acc1[r];
        }
      }
      __syncthreads();
      if (tid < 512) {
        #pragma unroll
        for (int i = 0; i < 2; ++i) {
          int ul = eu0 + i * 16;
          float ir  = gLDS[((0 * 3 + 0) * 32 + ul) * 32 + eb] + bir[i];
          float iz  = gLDS[((0 * 3 + 1) * 32 + ul) * 32 + eb] + biz[i];
          float in_ = gLDS[((0 * 3 + 2) * 32 + ul) * 32 + eb] + bin_[i];
          float hr  = gLDS[((1 * 3 + 0) * 32 + ul) * 32 + eb] + bhr[i];
          float hz  = gLDS[((1 * 3 + 1) * 32 + ul) * 32 + eb] + bhz[i];
          float hn  = gLDS[((1 * 3 + 2) * 32 + ul) * 32 + eb] + bhn[i];
          float r = sigm(ir + hr);
          float z = sigm(iz + hz);
          float n = tanhf(in_ + r * hn);
          float hnew = (1.f - z) * n + z * hprev[i];
          hprev[i] = hnew;
          f16_t hv = (f16_t)hnew;
          hstage[(eb >> 4) * 512 +
                 ((((ul >> 3) & 3) * 16) + (eb & 15)) * 8 + (ul & 7)] = hv;
          astage[eb * 32 + ul] = hv;
          if (t == NT - 1) hfin[16384 + eb * NH + ug + ul] = hnew;
        }
      }
      __syncthreads();
      if (tid < 256) {
        const int chunk = tid >> 7, w = tid & 127;
        const uint2 v = *(const uint2*)(hstage + chunk * 512 + w * 4);
        *(uint2*)(hb1 + (size_t)(t + 1) * 16384 + (chunk * 16 + g) * 512 + w * 4) = v;
      } else if (tid < 512) {
        const int i2 = tid - 256;                 // 0..255
        const int b = i2 >> 3, uo = (i2 & 7) * 4; // b 0..31, uo 0..28
        *(uint2*)(Abf + ((size_t)(b * 64 + t)) * 512 + ug + uo) =
            *(const uint2*)(astage + b * 32 + uo);
      }
      __syncthreads();
      if (tid == 0)
        __hip_atomic_store(f1 + g * 16, t + 1, __ATOMIC_RELEASE,
                           __HIP_MEMORY_SCOPE_AGENT);
    }
  }
}

// ---------------- output projection (f16 MFMA, m97-style) ----------------

__global__ __launch_bounds__(256) void k_gemm(const f16_t* __restrict__ A,
                                              const f16_t* __restrict__ Bw,
                                              const float* __restrict__ bout,
                                              float* __restrict__ C) {
  __shared__ __align__(16) f16_t As[2][128 * 32];
  __shared__ __align__(16) f16_t Bs[2][128 * 32];
  const int n0 = blockIdx.x * 128;
  const int m0 = blockIdx.y * 128;
  const int tid = threadIdx.x;
  const int wave = tid >> 6;
  const int lane = tid & 63;
  const int r_in = lane >> 2;
  const int c8 = (lane & 3) * 8;

  const f16_t* Ag = A  + (size_t)(m0 + wave * 32 + r_in) * NH + c8;
  const f16_t* Bg = Bw + (size_t)(n0 + wave * 32 + r_in) * NH + c8;

  auto stage = [&](int buf, int kk) {
    f16_t* la = &As[buf][(wave * 32) * 32];
    f16_t* lb = &Bs[buf][(wave * 32) * 32];
    __builtin_amdgcn_global_load_lds((gvoid_t*)(Ag + kk),            (lvoid_t*)la,             16, 0, 0);
    __builtin_amdgcn_global_load_lds((gvoid_t*)(Ag + kk + 16 * NH),  (lvoid_t*)(la + 16 * 32), 16, 0, 0);
    __builtin_amdgcn_global_load_lds((gvoid_t*)(Bg + kk),            (lvoid_t*)lb,             16, 0, 0);
    __builtin_amdgcn_global_load_lds((gvoid_t*)(Bg + kk + 16 * NH),  (lvoid_t*)(lb + 16 * 32), 16, 0, 0);
  };

  f32x4 acc[4][4];
  #pragma unroll
  for (int i = 0; i < 4; ++i)
    #pragma unroll
    for (int j = 0; j < 4; ++j)
      acc[i][j] = (f32x4){0.f, 0.f, 0.f, 0.f};

  const int wm = (wave >> 1) * 64;
  const int wn = (wave & 1) * 64;
  const int arow = lane & 15;
  const int kg = (lane >> 4) * 8;

  stage(0, 0);
  __syncthreads();
  for (int kt = 0; kt < NH / 32; ++kt) {
    const int buf = kt & 1;
    if (kt + 1 < NH / 32) stage(buf ^ 1, (kt + 1) * 32);
    f16x8 af[4], bfr[4];
    #pragma unroll
    for (int i = 0; i < 4; ++i) {
      af[i]  = *(const f16x8*)&As[buf][(wm + i * 16 + arow) * 32 + kg];
      bfr[i] = *(const f16x8*)&Bs[buf][(wn + i * 16 + arow) * 32 + kg];
    }
    #pragma unroll
    for (int i = 0; i < 4; ++i)
      #pragma unroll
      for (int j = 0; j < 4; ++j)
        acc[i][j] = __builtin_amdgcn_mfma_f32_16x16x32_f16(af[i], bfr[j], acc[i][j], 0, 0, 0);
    __syncthreads();
  }

  const int crow = (lane >> 4) * 4;
  const int ccol = lane & 15;
  #pragma unroll
  for (int j = 0; j < 4; ++j) {
    const int gcol = n0 + wn + j * 16 + ccol;
    const float bb = bout[gcol];
    #pragma unroll
    for (int i = 0; i < 4; ++i) {
      const int grow = m0 + wm + i * 16 + crow;
      #pragma unroll
      for (int r = 0; r < 4; ++r)
        C[(size_t)(grow + r) * NV + gcol] = acc[i][j][r] + bb;
    }
  }
}

// ---------------- in-place row log_softmax ----------------

__global__ __launch_bounds__(256) void k_lsm(float* __restrict__ out) {
  __shared__ f16_t row[NV];
  __shared__ float redm[4], reds[4];
  const int m = blockIdx.x;
  float* p = out + (size_t)m * NV;
  const int tid = threadIdx.x;
  float mx = -3.0e38f;
  for (int i = tid; i < NV; i += 256) {
    float x = p[i];
    row[i] = (f16_t)x;
    mx = fmaxf(mx, x);
  }
  #pragma unroll
  for (int o = 1; o < 64; o <<= 1) mx = fmaxf(mx, __shfl_xor(mx, o, 64));
  if ((tid & 63) == 0) redm[tid >> 6] = mx;
  __syncthreads();
  mx = fmaxf(fmaxf(redm[0], redm[1]), fmaxf(redm[2], redm[3]));
  float s = 0.f;
  for (int i = tid; i < NV; i += 256) s += __expf((float)row[i] - mx);
  #pragma unroll
  for (int o = 1; o < 64; o <<= 1) s += __shfl_xor(s, o, 64);
  if ((tid & 63) == 0) reds[tid >> 6] = s;
  __syncthreads();
  const float lse = mx + __logf(reds[0] + reds[1] + reds[2] + reds[3]);
  for (int i = tid; i < NV; i += 256) p[i] = (float)row[i] - lse;
}

// ws layout (bytes)
constexpr size_t WS_F0  = 0;      // 8 flags, 64B apart
constexpr size_t WS_F1  = 512;    // 16 flags, 64B apart
constexpr size_t WS_GI0 = 2048;
constexpr size_t WS_HB0 = WS_GI0 + sizeof(f16_t) * (size_t)NT * NG * NB;       // 6.29 MB
constexpr size_t WS_HB1 = WS_HB0 + sizeof(f16_t) * (size_t)(NT + 1) * NH * NB; // +2.13 MB
constexpr size_t WS_ABF = WS_HB1 + sizeof(f16_t) * (size_t)(NT + 1) * NH * NB;
constexpr size_t WS_WF  = WS_ABF + sizeof(f16_t) * (size_t)NM * NH;

}  // namespace

extern "C" void kernel_launch(void* const* d_in, const int* in_sizes, int n_in,
                              void* d_out, int out_size, void* d_ws, size_t ws_size,
                              hipStream_t stream) {
  const float* enc_h = (const float*)d_in[1];
  const int*   tgt   = (const int*)d_in[2];
  const float* emb   = (const float*)d_in[3];
  const float* Wih0  = (const float*)d_in[4];
  const float* Whh0  = (const float*)d_in[5];
  const float* bih0  = (const float*)d_in[6];
  const float* bhh0  = (const float*)d_in[7];
  const float* Wih1  = (const float*)d_in[8];
  const float* Whh1  = (const float*)d_in[9];
  const float* bih1  = (const float*)d_in[10];
  const float* bhh1  = (const float*)d_in[11];
  const float* Wout  = (const float*)d_in[12];
  const float* bout  = (const float*)d_in[13];

  char* ws = (char*)d_ws;
  int*    f0   = (int*)(ws + WS_F0);
  int*    f1   = (int*)(ws + WS_F1);
  f16_t*  Gi0  = (f16_t*)(ws + WS_GI0);
  f16_t*  hb0  = (f16_t*)(ws + WS_HB0);
  f16_t*  hb1  = (f16_t*)(ws + WS_HB1);
  f16_t*  Abf  = (f16_t*)(ws + WS_ABF);
  f16_t*  Wf   = (f16_t*)(ws + WS_WF);

  float* out  = (float*)d_out;
  float* hfin = out + (size_t)NM * NV;

  hipMemsetAsync(ws, 0, 2048, stream);
  k_hinit<<<(2 * NB * NH) / 256, 256, 0, stream>>>(enc_h, hb0, hb1);
  k_gi0<<<dim3(NG / 64, NT), 256, 0, stream>>>(tgt, emb, Wih0, bih0, Gi0);
  k_rnn2<<<24, 768, 0, stream>>>(Gi0, Whh0, bhh0, Wih1, bih1, Whh1, bhh1,
                                 enc_h, hb0, hb1, Abf, hfin, f0, f1);
  k_wcvt<<<(NV * NH / 4) / 256, 256, 0, stream>>>(Wout, Wf);
  k_gemm<<<dim3(NV / 128, NM / 128), 256, 0, stream>>>(Abf, Wf, bout, out);
  k_lsm<<<NM, 256, 0, stream>>>(out);
}

// Round 7
// 970.897 us; speedup vs baseline: 1.9930x; 1.0002x over previous
//
#include <hip/hip_runtime.h>
#include <hip/hip_bf16.h>

namespace {

constexpr int NV = 32000;
constexpr int NE = 256;
constexpr int NH = 512;
constexpr int NB = 32;
constexpr int NT = 64;
constexpr int NG = 3 * NH;    // 1536
constexpr int NM = NB * NT;   // 2048
constexpr int SOS = 1;

typedef _Float16 f16_t;
typedef _Float16 f16x8 __attribute__((ext_vector_type(8)));
typedef _Float16 f16x2 __attribute__((ext_vector_type(2)));
typedef float f32x4 __attribute__((ext_vector_type(4)));

typedef __attribute__((address_space(1))) void gvoid_t;
typedef __attribute__((address_space(3))) void lvoid_t;

// fragment-order offset of h[u][b] inside a 512x32 f16 step buffer.
// B-frag of mfma_f32_16x16x32_f16: lane l holds col n=l&15, k=(l>>4)*8+j.
__device__ __forceinline__ int fragoff(int u, int b) {
  return ((b >> 4) * 16 + (u >> 5)) * 512 +
         ((((u >> 3) & 3) * 16) + (b & 15)) * 8 + (u & 7);
}

__device__ __forceinline__ void load_wf(const float* wrow, f16x8* wf) {
  #pragma unroll
  for (int kc = 0; kc < 16; ++kc) {
    f32x4 a = *(const f32x4*)(wrow + kc * 32);
    f32x4 c = *(const f32x4*)(wrow + kc * 32 + 4);
    f16x8 w;
    w[0] = (f16_t)a[0]; w[1] = (f16_t)a[1]; w[2] = (f16_t)a[2]; w[3] = (f16_t)a[3];
    w[4] = (f16_t)c[0]; w[5] = (f16_t)c[1]; w[6] = (f16_t)c[2]; w[7] = (f16_t)c[3];
    wf[kc] = w;
  }
}

__device__ __forceinline__ float sigm(float x) { return 1.f / (1.f + __expf(-x)); }

// Per-block flag words, each on its own 64B line (int stride 16).
__device__ __forceinline__ void wait_flag(int* p, int target) {
  while (__hip_atomic_load(p, __ATOMIC_RELAXED, __HIP_MEMORY_SCOPE_AGENT) < target)
    __builtin_amdgcn_s_sleep(1);
}

// Round-7: WRITE-THROUGH 8B data stores (relaxed agent atomics, sc0 sc1).
// Keeps the local L2 clean so the per-step release flag-store has no dirty-L2
// writeback walk to perform (the R3-R6 constant ~5us/step suspect).
__device__ __forceinline__ void store8(void* dst, unsigned long long v) {
  __hip_atomic_store((unsigned long long*)dst, v, __ATOMIC_RELAXED,
                     __HIP_MEMORY_SCOPE_AGENT);
}

// ---------------- prologue kernels ----------------

__global__ __launch_bounds__(256) void k_hinit(const float* __restrict__ eh,
                                               f16_t* __restrict__ hb0,
                                               f16_t* __restrict__ hb1) {
  int idx = blockIdx.x * 256 + threadIdx.x;   // l*16384 + b*512 + u
  int u = idx & 511;
  int b = (idx >> 9) & 31;
  int l = idx >> 14;
  f16_t v = (f16_t)eh[idx];
  (l ? hb1 : hb0)[fragoff(u, b)] = v;
}

__global__ __launch_bounds__(256) void k_wcvt(const float* __restrict__ w,
                                              f16_t* __restrict__ wb) {
  int idx = blockIdx.x * 256 + threadIdx.x;   // < NV*NH/4
  f32x4 v = ((const f32x4*)w)[idx];
  f16x2 o0, o1;
  o0[0] = (f16_t)v[0]; o0[1] = (f16_t)v[1];
  o1[0] = (f16_t)v[2]; o1[1] = (f16_t)v[3];
  ((f16x2*)wb)[2 * idx] = o0;
  ((f16x2*)wb)[2 * idx + 1] = o1;
}

__global__ __launch_bounds__(256) void k_gi0(const int* __restrict__ tgt,
                                             const float* __restrict__ emb,
                                             const float* __restrict__ Wih0,
                                             const float* __restrict__ bih0,
                                             f16_t* __restrict__ Gi0) {
  __shared__ float xs[NE * NB];   // [e][b]
  __shared__ int toks[NB];
  const int t = blockIdx.y;
  const int tid = threadIdx.x;
  if (tid < NB) toks[tid] = (t == 0) ? SOS : tgt[tid * NT + (t - 1)];
  __syncthreads();
  {
    const int b = tid >> 3, e0 = (tid & 7) * 32;
    const float* er = emb + (size_t)toks[b] * NE + e0;
    #pragma unroll 8
    for (int i = 0; i < 32; ++i) {
      float v = er[i];
      xs[(e0 + i) * NB + b] = v > 0.f ? v : 0.f;
    }
  }
  __syncthreads();
  const int b = tid & 31;
  #pragma unroll
  for (int jj = 0; jj < 8; ++jj) {
    const int j = blockIdx.x * 64 + jj * 8 + (tid >> 5);
    float acc = bih0[j];
    const f32x4* wr = (const f32x4*)(Wih0 + (size_t)j * NE);
    #pragma unroll 4
    for (int e4 = 0; e4 < NE / 4; ++e4) {
      f32x4 w = wr[e4];
      acc += w[0] * xs[(4 * e4 + 0) * NB + b] + w[1] * xs[(4 * e4 + 1) * NB + b]
           + w[2] * xs[(4 * e4 + 2) * NB + b] + w[3] * xs[(4 * e4 + 3) * NB + b];
    }
    Gi0[((size_t)t * NG + j) * NB + b] = (f16_t)acc;
  }
}

// ---------------- persistent MFMA recurrence ----------------
// blocks 0..7: layer 0 (64 units each).  blocks 8..23: layer 1 (32 units each).
// h passed via per-step frag-order f16 buffers hb0[t], hb1[t] (t=0 is initial).
// Sync: per-block flag lines, parallel polls, release-store publish (R6).
// Data: write-through 8B atomic stores -> clean L2 at release time (R7).

__global__ __launch_bounds__(768) void k_rnn2(
    const f16_t* __restrict__ Gi0,
    const float* __restrict__ Whh0, const float* __restrict__ bhh0,
    const float* __restrict__ Wih1, const float* __restrict__ bih1,
    const float* __restrict__ Whh1, const float* __restrict__ bhh1,
    const float* __restrict__ eh,
    f16_t* __restrict__ hb0, f16_t* __restrict__ hb1,
    f16_t* __restrict__ Abf, float* __restrict__ hfin,
    int* f0, int* f1) {
  __shared__ __align__(16) float gLDS[6144];      // 24 KB
  __shared__ __align__(16) f16_t hstage[2048];    // 4 KB
  __shared__ __align__(16) f16_t astage[1024];    // 2 KB
  const int tid = threadIdx.x;
  const int wave = tid >> 6, lane = tid & 63;
  const int bid = blockIdx.x;
  const int eb = tid & 31, eu0 = (tid >> 5) & 15;

  if (bid < 8) {
    // ---------------- layer 0 ----------------
    const int ug = bid * 64;
    const int gate = wave >> 2, tile = wave & 3;
    const int row = gate * 512 + ug + tile * 16 + (lane & 15);
    f16x8 wf[16];
    load_wf(Whh0 + (size_t)row * NH + (lane >> 4) * 8, wf);

    float hprev[4], br[4], bz[4], bn[4];
    if (tid < 512) {
      #pragma unroll
      for (int i = 0; i < 4; ++i) {
        int u = ug + eu0 + i * 16;
        hprev[i] = eh[eb * NH + u];
        br[i] = bhh0[u]; bz[i] = bhh0[512 + u]; bn[i] = bhh0[1024 + u];
      }
    }

    for (int t = 0; t < NT; ++t) {
      float gr[4], gz[4], gn[4];
      if (tid < 512) {                       // prefetch gi (overlaps the wait)
        const f16_t* g = Gi0 + (size_t)t * NG * NB;
        #pragma unroll
        for (int i = 0; i < 4; ++i) {
          int u = ug + eu0 + i * 16;
          gr[i] = (float)g[u * NB + eb];
          gz[i] = (float)g[(512 + u) * NB + eb];
          gn[i] = (float)g[(1024 + u) * NB + eb];
        }
      }
      if (t > 0) {
        if (tid < 8) wait_flag(f0 + tid * 16, t);   // all 8 flags polled in parallel
        if (tid == 0) __builtin_amdgcn_fence(__ATOMIC_ACQUIRE, "agent");
      }
      __syncthreads();
      const f16_t* hb = hb0 + (size_t)t * 16384;
      f32x4 acc0 = {0.f, 0.f, 0.f, 0.f}, acc1 = {0.f, 0.f, 0.f, 0.f};
      #pragma unroll
      for (int kc = 0; kc < 16; ++kc) {
        f16x8 b0 = *(const f16x8*)(hb + kc * 512 + lane * 8);
        f16x8 b1 = *(const f16x8*)(hb + (16 + kc) * 512 + lane * 8);
        acc0 = __builtin_amdgcn_mfma_f32_16x16x32_f16(wf[kc], b0, acc0, 0, 0, 0);
        acc1 = __builtin_amdgcn_mfma_f32_16x16x32_f16(wf[kc], b1, acc1, 0, 0, 0);
      }
      {
        const int m0 = (lane >> 4) * 4, col = lane & 15;
        #pragma unroll
        for (int r = 0; r < 4; ++r) {
          int ul = tile * 16 + m0 + r;
          gLDS[(gate * 64 + ul) * 32 + col] = acc0[r];
          gLDS[(gate * 64 + ul) * 32 + 16 + col] = acc1[r];
        }
      }
      __syncthreads();
      if (tid < 512) {
        #pragma unroll
        for (int i = 0; i < 4; ++i) {
          int ul = eu0 + i * 16;
          float rt = gLDS[(0 * 64 + ul) * 32 + eb];
          float zt = gLDS[(1 * 64 + ul) * 32 + eb];
          float nt_ = gLDS[(2 * 64 + ul) * 32 + eb];
          float r = sigm(gr[i] + rt + br[i]);
          float z = sigm(gz[i] + zt + bz[i]);
          float n = tanhf(gn[i] + r * (nt_ + bn[i]));
          float hnew = (1.f - z) * n + z * hprev[i];
          hprev[i] = hnew;
          hstage[((eb >> 4) * 2 + (ul >> 5)) * 512 +
                 ((((ul >> 3) & 3) * 16) + (eb & 15)) * 8 + (ul & 7)] = (f16_t)hnew;
          if (t == NT - 1) hfin[eb * NH + ug + ul] = hnew;
        }
      }
      __syncthreads();
      if (tid < 512) {
        const int chunk = tid >> 7, w = tid & 127;
        const unsigned long long v =
            *(const unsigned long long*)(hstage + chunk * 512 + w * 4);
        store8(hb0 + (size_t)(t + 1) * 16384 +
               ((chunk >> 1) * 16 + (ug >> 5) + (chunk & 1)) * 512 + w * 4, v);
      }
      __syncthreads();
      if (tid == 0)
        __hip_atomic_store(f0 + bid * 16, t + 1, __ATOMIC_RELEASE,
                           __HIP_MEMORY_SCOPE_AGENT);
    }
  } else {
    // ---------------- layer 1 ----------------
    const int g = bid - 8, ug = g * 32;
    const int mm = wave >= 6;                 // 0: Wih1 (x=h0), 1: Whh1 (h1)
    const int w6 = mm ? wave - 6 : wave;
    const int gate = w6 >> 1, tile = w6 & 1;
    const int row = gate * 512 + ug + tile * 16 + (lane & 15);
    const float* W = mm ? Whh1 : Wih1;
    f16x8 wf[16];
    load_wf(W + (size_t)row * NH + (lane >> 4) * 8, wf);

    float hprev[2], bir[2], biz[2], bin_[2], bhr[2], bhz[2], bhn[2];
    if (tid < 512) {
      #pragma unroll
      for (int i = 0; i < 2; ++i) {
        int u = ug + eu0 + i * 16;
        hprev[i] = eh[16384 + eb * NH + u];
        bir[i] = bih1[u]; biz[i] = bih1[512 + u]; bin_[i] = bih1[1024 + u];
        bhr[i] = bhh1[u]; bhz[i] = bhh1[512 + u]; bhn[i] = bhh1[1024 + u];
      }
    }

    for (int t = 0; t < NT; ++t) {
      if (tid < 24) {                        // parallel poll: 8x f0, 16x f1
        int* p   = (tid < 8) ? (f0 + tid * 16) : (f1 + (tid - 8) * 16);
        int tgt  = (tid < 8) ? (t + 1) : t;
        wait_flag(p, tgt);
      }
      if (tid == 0) __builtin_amdgcn_fence(__ATOMIC_ACQUIRE, "agent");
      __syncthreads();
      const f16_t* hb = mm ? (hb1 + (size_t)t * 16384)
                           : (hb0 + (size_t)(t + 1) * 16384);
      f32x4 acc0 = {0.f, 0.f, 0.f, 0.f}, acc1 = {0.f, 0.f, 0.f, 0.f};
      #pragma unroll
      for (int kc = 0; kc < 16; ++kc) {
        f16x8 b0 = *(const f16x8*)(hb + kc * 512 + lane * 8);
        f16x8 b1 = *(const f16x8*)(hb + (16 + kc) * 512 + lane * 8);
        acc0 = __builtin_amdgcn_mfma_f32_16x16x32_f16(wf[kc], b0, acc0, 0, 0, 0);
        acc1 = __builtin_amdgcn_mfma_f32_16x16x32_f16(wf[kc], b1, acc1, 0, 0, 0);
      }
      {
        const int m0 = (lane >> 4) * 4, col = lane & 15;
        #pragma unroll
        for (int r = 0; r < 4; ++r) {
          int ul = tile * 16 + m0 + r;
          gLDS[((mm * 3 + gate) * 32 + ul) * 32 + col] = acc0[r];
          gLDS[((mm * 3 + gate) * 32 + ul) * 32 + 16 + col] = acc1[r];
        }
      }
      __syncthreads();
      if (tid < 512) {
        #pragma unroll
        for (int i = 0; i < 2; ++i) {
          int ul = eu0 + i * 16;
          float ir  = gLDS[((0 * 3 + 0) * 32 + ul) * 32 + eb] + bir[i];
          float iz  = gLDS[((0 * 3 + 1) * 32 + ul) * 32 + eb] + biz[i];
          float in_ = gLDS[((0 * 3 + 2) * 32 + ul) * 32 + eb] + bin_[i];
          float hr  = gLDS[((1 * 3 + 0) * 32 + ul) * 32 + eb] + bhr[i];
          float hz  = gLDS[((1 * 3 + 1) * 32 + ul) * 32 + eb] + bhz[i];
          float hn  = gLDS[((1 * 3 + 2) * 32 + ul) * 32 + eb] + bhn[i];
          float r = sigm(ir + hr);
          float z = sigm(iz + hz);
          float n = tanhf(in_ + r * hn);
          float hnew = (1.f - z) * n + z * hprev[i];
          hprev[i] = hnew;
          f16_t hv = (f16_t)hnew;
          hstage[(eb >> 4) * 512 +
                 ((((ul >> 3) & 3) * 16) + (eb & 15)) * 8 + (ul & 7)] = hv;
          astage[eb * 32 + ul] = hv;
          if (t == NT - 1) hfin[16384 + eb * NH + ug + ul] = hnew;
        }
      }
      __syncthreads();
      if (tid < 256) {
        const int chunk = tid >> 7, w = tid & 127;
        const unsigned long long v =
            *(const unsigned long long*)(hstage + chunk * 512 + w * 4);
        store8(hb1 + (size_t)(t + 1) * 16384 + (chunk * 16 + g) * 512 + w * 4, v);
      } else if (tid < 512) {
        const int i2 = tid - 256;                 // 0..255
        const int b = i2 >> 3, uo = (i2 & 7) * 4; // b 0..31, uo 0..28
        store8(Abf + ((size_t)(b * 64 + t)) * 512 + ug + uo,
               *(const unsigned long long*)(astage + b * 32 + uo));
      }
      __syncthreads();
      if (tid == 0)
        __hip_atomic_store(f1 + g * 16, t + 1, __ATOMIC_RELEASE,
                           __HIP_MEMORY_SCOPE_AGENT);
    }
  }
}

// ---------------- output projection (f16 MFMA, m97-style) ----------------

__global__ __launch_bounds__(256) void k_gemm(const f16_t* __restrict__ A,
                                              const f16_t* __restrict__ Bw,
                                              const float* __restrict__ bout,
                                              float* __restrict__ C) {
  __shared__ __align__(16) f16_t As[2][128 * 32];
  __shared__ __align__(16) f16_t Bs[2][128 * 32];
  const int n0 = blockIdx.x * 128;
  const int m0 = blockIdx.y * 128;
  const int tid = threadIdx.x;
  const int wave = tid >> 6;
  const int lane = tid & 63;
  const int r_in = lane >> 2;
  const int c8 = (lane & 3) * 8;

  const f16_t* Ag = A  + (size_t)(m0 + wave * 32 + r_in) * NH + c8;
  const f16_t* Bg = Bw + (size_t)(n0 + wave * 32 + r_in) * NH + c8;

  auto stage = [&](int buf, int kk) {
    f16_t* la = &As[buf][(wave * 32) * 32];
    f16_t* lb = &Bs[buf][(wave * 32) * 32];
    __builtin_amdgcn_global_load_lds((gvoid_t*)(Ag + kk),            (lvoid_t*)la,             16, 0, 0);
    __builtin_amdgcn_global_load_lds((gvoid_t*)(Ag + kk + 16 * NH),  (lvoid_t*)(la + 16 * 32), 16, 0, 0);
    __builtin_amdgcn_global_load_lds((gvoid_t*)(Bg + kk),            (lvoid_t*)lb,             16, 0, 0);
    __builtin_amdgcn_global_load_lds((gvoid_t*)(Bg + kk + 16 * NH),  (lvoid_t*)(lb + 16 * 32), 16, 0, 0);
  };

  f32x4 acc[4][4];
  #pragma unroll
  for (int i = 0; i < 4; ++i)
    #pragma unroll
    for (int j = 0; j < 4; ++j)
      acc[i][j] = (f32x4){0.f, 0.f, 0.f, 0.f};

  const int wm = (wave >> 1) * 64;
  const int wn = (wave & 1) * 64;
  const int arow = lane & 15;
  const int kg = (lane >> 4) * 8;

  stage(0, 0);
  __syncthreads();
  for (int kt = 0; kt < NH / 32; ++kt) {
    const int buf = kt & 1;
    if (kt + 1 < NH / 32) stage(buf ^ 1, (kt + 1) * 32);
    f16x8 af[4], bfr[4];
    #pragma unroll
    for (int i = 0; i < 4; ++i) {
      af[i]  = *(const f16x8*)&As[buf][(wm + i * 16 + arow) * 32 + kg];
      bfr[i] = *(const f16x8*)&Bs[buf][(wn + i * 16 + arow) * 32 + kg];
    }
    #pragma unroll
    for (int i = 0; i < 4; ++i)
      #pragma unroll
      for (int j = 0; j < 4; ++j)
        acc[i][j] = __builtin_amdgcn_mfma_f32_16x16x32_f16(af[i], bfr[j], acc[i][j], 0, 0, 0);
    __syncthreads();
  }

  const int crow = (lane >> 4) * 4;
  const int ccol = lane & 15;
  #pragma unroll
  for (int j = 0; j < 4; ++j) {
    const int gcol = n0 + wn + j * 16 + ccol;
    const float bb = bout[gcol];
    #pragma unroll
    for (int i = 0; i < 4; ++i) {
      const int grow = m0 + wm + i * 16 + crow;
      #pragma unroll
      for (int r = 0; r < 4; ++r)
        C[(size_t)(grow + r) * NV + gcol] = acc[i][j][r] + bb;
    }
  }
}

// ---------------- in-place row log_softmax ----------------

__global__ __launch_bounds__(256) void k_lsm(float* __restrict__ out) {
  __shared__ f16_t row[NV];
  __shared__ float redm[4], reds[4];
  const int m = blockIdx.x;
  float* p = out + (size_t)m * NV;
  const int tid = threadIdx.x;
  float mx = -3.0e38f;
  for (int i = tid; i < NV; i += 256) {
    float x = p[i];
    row[i] = (f16_t)x;
    mx = fmaxf(mx, x);
  }
  #pragma unroll
  for (int o = 1; o < 64; o <<= 1) mx = fmaxf(mx, __shfl_xor(mx, o, 64));
  if ((tid & 63) == 0) redm[tid >> 6] = mx;
  __syncthreads();
  mx = fmaxf(fmaxf(redm[0], redm[1]), fmaxf(redm[2], redm[3]));
  float s = 0.f;
  for (int i = tid; i < NV; i += 256) s += __expf((float)row[i] - mx);
  #pragma unroll
  for (int o = 1; o < 64; o <<= 1) s += __shfl_xor(s, o, 64);
  if ((tid & 63) == 0) reds[tid >> 6] = s;
  __syncthreads();
  const float lse = mx + __logf(reds[0] + reds[1] + reds[2] + reds[3]);
  for (int i = tid; i < NV; i += 256) p[i] = (float)row[i] - lse;
}

// ws layout (bytes)
constexpr size_t WS_F0  = 0;      // 8 flags, 64B apart
constexpr size_t WS_F1  = 512;    // 16 flags, 64B apart
constexpr size_t WS_GI0 = 2048;
constexpr size_t WS_HB0 = WS_GI0 + sizeof(f16_t) * (size_t)NT * NG * NB;       // 6.29 MB
constexpr size_t WS_HB1 = WS_HB0 + sizeof(f16_t) * (size_t)(NT + 1) * NH * NB; // +2.13 MB
constexpr size_t WS_ABF = WS_HB1 + sizeof(f16_t) * (size_t)(NT + 1) * NH * NB;
constexpr size_t WS_WF  = WS_ABF + sizeof(f16_t) * (size_t)NM * NH;

}  // namespace

extern "C" void kernel_launch(void* const* d_in, const int* in_sizes, int n_in,
                              void* d_out, int out_size, void* d_ws, size_t ws_size,
                              hipStream_t stream) {
  const float* enc_h = (const float*)d_in[1];
  const int*   tgt   = (const int*)d_in[2];
  const float* emb   = (const float*)d_in[3];
  const float* Wih0  = (const float*)d_in[4];
  const float* Whh0  = (const float*)d_in[5];
  const float* bih0  = (const float*)d_in[6];
  const float* bhh0  = (const float*)d_in[7];
  const float* Wih1  = (const float*)d_in[8];
  const float* Whh1  = (const float*)d_in[9];
  const float* bih1  = (const float*)d_in[10];
  const float* bhh1  = (const float*)d_in[11];
  const float* Wout  = (const float*)d_in[12];
  const float* bout  = (const float*)d_in[13];

  char* ws = (char*)d_ws;
  int*    f0   = (int*)(ws + WS_F0);
  int*    f1   = (int*)(ws + WS_F1);
  f16_t*  Gi0  = (f16_t*)(ws + WS_GI0);
  f16_t*  hb0  = (f16_t*)(ws + WS_HB0);
  f16_t*  hb1  = (f16_t*)(ws + WS_HB1);
  f16_t*  Abf  = (f16_t*)(ws + WS_ABF);
  f16_t*  Wf   = (f16_t*)(ws + WS_WF);

  float* out  = (float*)d_out;
  float* hfin = out + (size_t)NM * NV;

  hipMemsetAsync(ws, 0, 2048, stream);
  k_hinit<<<(2 * NB * NH) / 256, 256, 0, stream>>>(enc_h, hb0, hb1);
  k_gi0<<<dim3(NG / 64, NT), 256, 0, stream>>>(tgt, emb, Wih0, bih0, Gi0);
  k_rnn2<<<24, 768, 0, stream>>>(Gi0, Whh0, bhh0, Wih1, bih1, Whh1, bhh1,
                                 enc_h, hb0, hb1, Abf, hfin, f0, f1);
  k_wcvt<<<(NV * NH / 4) / 256, 256, 0, stream>>>(Wout, Wf);
  k_gemm<<<dim3(NV / 128, NM / 128), 256, 0, stream>>>(Abf, Wf, bout, out);
  k_lsm<<<NM, 256, 0, stream>>>(out);
}